// Round 4
// baseline (218.087 us; speedup 1.0000x reference)
//
#include <hip/hip_runtime.h>

// Problem: attention, q,k,v [B=4, N=2048, H=8, D=64] fp32 -> out same.
#define B 4
#define N 2048
#define H 8
#define D 64
#define HD 512              // row stride (elements) for fixed (b,h)
#define QT 128              // q rows per block (4 waves x 32)
#define KT 64               // keys per tile
#define NTILES (N / KT)     // 32
#define PLS 72              // P buffer row stride (halves): 144B, non-pow2

typedef _Float16 half8 __attribute__((ext_vector_type(8)));
typedef _Float16 half4 __attribute__((ext_vector_type(4)));
typedef float float4_ __attribute__((ext_vector_type(4)));

// ---------------- fused prepass: K f32->f16 same layout; V -> Vt [b,h,d,n] f16 ----------------
__global__ void prep_kernel(const float* __restrict__ K, const float* __restrict__ V,
                            _Float16* __restrict__ Kf, _Float16* __restrict__ Vtr) {
    __shared__ _Float16 tile[64][PLS];
    const int t = threadIdx.x;
    if (blockIdx.x < 2048) {
        const size_t i = (size_t)blockIdx.x * 256 + t;
        const float4_* p = (const float4_*)(K + i * 8);
        float4_ a = p[0], b = p[1];
        half8 hh;
        #pragma unroll
        for (int j = 0; j < 4; ++j) { hh[j] = (_Float16)a[j]; hh[4 + j] = (_Float16)b[j]; }
        *(half8*)(Kf + i * 8) = hh;
    } else {
        const int bid = blockIdx.x - 2048;
        const int nt = bid & 31, h = (bid >> 5) & 7, b = bid >> 8;
        {
            const int i = t >> 2, c0 = (t & 3) * 16;
            const float* vp = V + (size_t)b * N * HD + (size_t)(nt * 64 + i) * HD + h * D + c0;
            #pragma unroll
            for (int j = 0; j < 4; ++j) {
                float4_ a = *(const float4_*)(vp + j * 4);
                #pragma unroll
                for (int c = 0; c < 4; ++c) tile[i][c0 + j * 4 + c] = (_Float16)a[c];
            }
        }
        __syncthreads();
        {
            const int d = t >> 2, n0 = (t & 3) * 16;
            half8 lo, hi;
            #pragma unroll
            for (int j = 0; j < 8; ++j) { lo[j] = tile[n0 + j][d]; hi[j] = tile[n0 + 8 + j][d]; }
            _Float16* op = Vtr + ((size_t)(b * H + h) * D + d) * N + nt * 64 + n0;
            *(half8*)op = lo;
            *(half8*)(op + 8) = hi;
        }
    }
}

// ---------------- main: flash attention, S^T form, frags direct from L2, no barriers ----------------
__global__ __launch_bounds__(256, 2)
void fattn4_kernel(const float* __restrict__ Q, const _Float16* __restrict__ Kf,
                   const _Float16* __restrict__ Vt, float* __restrict__ Out)
{
    __shared__ __align__(16) _Float16 Pw[4][32][PLS];   // ONLY LDS: per-wave P [q local][key]

    const int tid  = threadIdx.x;
    const int wave = tid >> 6;
    const int lane = tid & 63;
    const int m    = lane & 15;
    const int quad = lane >> 4;

    // XCD-aware remap: blocks with i%8==c handle (b*8+h)%8==c -> per-XCD K/V
    // working set = 4 (b,h) pairs = 4MB f16, fits the 4MB private L2.
    const int i  = blockIdx.x;            // 0..511
    const int c  = i & 7;
    const int j  = i >> 3;
    const int bh = c + 8 * (j & 3);       // 0..31
    const int qt = j >> 2;                // 0..15
    const int b  = bh >> 3;
    const int h  = bh & 7;
    const int q_base = qt * QT + wave * 32;

    const size_t bh_q = (size_t)b * N * HD + (size_t)h * D;
    const _Float16* Kbh = Kf + bh_q;
    const _Float16* Vbh = Vt + (size_t)(b * H + h) * D * N;

    // Q fragments (held in regs all kernel), scale*log2e folded
    const float SC = 0.125f * 1.4426950408889634f;
    half8 qf[2][2];
    #pragma unroll
    for (int u = 0; u < 2; ++u) {
        const float* qp = Q + bh_q + (size_t)(q_base + u * 16 + m) * HD + quad * 8;
        float4_ a0 = *(const float4_*)qp,        a1 = *(const float4_*)(qp + 4);
        float4_ b0 = *(const float4_*)(qp + 32), b1 = *(const float4_*)(qp + 36);
        #pragma unroll
        for (int jj = 0; jj < 4; ++jj) {
            qf[u][0][jj] = (_Float16)(a0[jj] * SC); qf[u][0][4 + jj] = (_Float16)(a1[jj] * SC);
            qf[u][1][jj] = (_Float16)(b0[jj] * SC); qf[u][1][4 + jj] = (_Float16)(b1[jj] * SC);
        }
    }

    float4_ o[2][4] = {};            // C-layout: q = u*16 + quad*4 + r, d = db*16 + m
    float lsum[2] = {0.f, 0.f};      // per-lane column sum for q = u*16 + m

    for (int t = 0; t < NTILES; ++t) {
        const int keybase = t * KT;

        // ---- issue all frag loads for this tile up front (L2-resident) ----
        half8 kfr[4][2];   // [key blk][k-chunk]: K[key=blk*16+m][d = (kc*4+quad)*8 ..+8]
        #pragma unroll
        for (int blk = 0; blk < 4; ++blk) {
            const _Float16* kp = Kbh + (size_t)(keybase + blk * 16 + m) * HD + quad * 8;
            kfr[blk][0] = *(const half8*)kp;
            kfr[blk][1] = *(const half8*)(kp + 32);
        }
        half8 vfr[2][4];   // [ks][d blk]: V^T[d=db*16+m][key = keybase + (ks*4+quad)*8 ..+8]
        #pragma unroll
        for (int ks = 0; ks < 2; ++ks)
            #pragma unroll
            for (int db = 0; db < 4; ++db)
                vfr[ks][db] = *(const half8*)(Vbh + (size_t)(db * 16 + m) * N
                                              + keybase + (ks * 4 + quad) * 8);

        // ---- S^T = K (Q*sc)^T ; P = exp2(S^T); column sums; P -> per-wave LDS ----
        #pragma unroll
        for (int blk = 0; blk < 4; ++blk) {
            #pragma unroll
            for (int u = 0; u < 2; ++u) {
                float4_ acc = {};
                acc = __builtin_amdgcn_mfma_f32_16x16x32_f16(kfr[blk][0], qf[u][0], acc, 0, 0, 0);
                acc = __builtin_amdgcn_mfma_f32_16x16x32_f16(kfr[blk][1], qf[u][1], acc, 0, 0, 0);
                half4 pk;
                #pragma unroll
                for (int r = 0; r < 4; ++r) {
                    float p = __builtin_amdgcn_exp2f(acc[r]);
                    lsum[u] += p;
                    pk[r] = (_Float16)p;
                }
                *(half4*)&Pw[wave][u * 16 + m][blk * 16 + quad * 4] = pk;
            }
        }
        // same-wave DS ordering (compiler lgkmcnt) covers write->read; no barrier needed

        // ---- O += P V ----
        half8 af[2][2];
        #pragma unroll
        for (int u = 0; u < 2; ++u) {
            af[u][0] = *(const half8*)&Pw[wave][u * 16 + m][quad * 8];
            af[u][1] = *(const half8*)&Pw[wave][u * 16 + m][32 + quad * 8];
        }
        #pragma unroll
        for (int ks = 0; ks < 2; ++ks)
            #pragma unroll
            for (int db = 0; db < 4; ++db)
                #pragma unroll
                for (int u = 0; u < 2; ++u)
                    o[u][db] = __builtin_amdgcn_mfma_f32_16x16x32_f16(af[u][ks], vfr[ks][db], o[u][db], 0, 0, 0);
    }

    // ---- finalize: reduce column sums, broadcast to C-layout rows, store ----
    float inv[2];
    #pragma unroll
    for (int u = 0; u < 2; ++u) {
        float v = lsum[u];
        v += __shfl_xor(v, 16, 64);
        v += __shfl_xor(v, 32, 64);
        inv[u] = 1.0f / v;
    }
    #pragma unroll
    for (int u = 0; u < 2; ++u) {
        #pragma unroll
        for (int r = 0; r < 4; ++r) {
            const int src = (lane & 48) | (quad * 4 + r);
            const float linv = __shfl(inv[u], src, 64);
            const int row = q_base + u * 16 + quad * 4 + r;
            #pragma unroll
            for (int db = 0; db < 4; ++db)
                Out[bh_q + (size_t)row * HD + db * 16 + m] = o[u][db][r] * linv;
        }
    }
}

// ---------------- fallback (round-1 verified kernel) if ws too small ----------------
__global__ __launch_bounds__(256, 2)
void fattn_fb_kernel(const float* __restrict__ Q, const float* __restrict__ K,
                     const float* __restrict__ V, float* __restrict__ Out)
{
    __shared__ __align__(16) _Float16 Ks[KT][PLS];
    __shared__ __align__(16) _Float16 Vts[D][PLS];
    __shared__ __align__(16) _Float16 Pw[4][16][PLS];
    const int tid = threadIdx.x, wave = tid >> 6, lane = tid & 63;
    const int m = lane & 15, quad = lane >> 4;
    const int q_base = blockIdx.x * 64;
    const size_t bh_off = ((size_t)blockIdx.z * N * H + (size_t)blockIdx.y) * D;
    const float SCALE = 0.125f;
    const int qrow = q_base + wave * 16 + m;
    const float* qp = Q + bh_off + (size_t)qrow * HD + quad * 8;
    half8 qf0, qf1;
    #pragma unroll
    for (int j = 0; j < 8; ++j) qf0[j] = (_Float16)(qp[j] * SCALE);
    #pragma unroll
    for (int j = 0; j < 8; ++j) qf1[j] = (_Float16)(qp[32 + j] * SCALE);
    float4_ o[4] = {};
    float mi[4], li[4];
    #pragma unroll
    for (int r = 0; r < 4; ++r) { mi[r] = -1e30f; li[r] = 0.0f; }
    for (int kt = 0; kt < N; kt += KT) {
        __syncthreads();
        {
            const int key = tid >> 2, c0 = (tid & 3) * 16;
            const float* kp = K + bh_off + (size_t)(kt + key) * HD + c0;
            half8 lo, hi;
            #pragma unroll
            for (int j = 0; j < 8; ++j) lo[j] = (_Float16)kp[j];
            #pragma unroll
            for (int j = 0; j < 8; ++j) hi[j] = (_Float16)kp[8 + j];
            *(half8*)&Ks[key][c0] = lo;
            *(half8*)&Ks[key][c0 + 8] = hi;
        }
        {
            const int c0 = (tid & 15) * 4, k0 = (tid >> 4) * 4;
            const float* vp = V + bh_off + (size_t)(kt + k0) * HD + c0;
            #pragma unroll
            for (int c = 0; c < 4; ++c)
                #pragma unroll
                for (int i = 0; i < 4; ++i)
                    Vts[c0 + c][k0 + i] = (_Float16)vp[i * HD + c];
        }
        __syncthreads();
        float4_ s[4];
        #pragma unroll
        for (int blk = 0; blk < 4; ++blk) {
            const int key = blk * 16 + m;
            half8 kf0 = *(const half8*)&Ks[key][quad * 8];
            half8 kf1 = *(const half8*)&Ks[key][32 + quad * 8];
            float4_ acc = {};
            acc = __builtin_amdgcn_mfma_f32_16x16x32_f16(qf0, kf0, acc, 0, 0, 0);
            acc = __builtin_amdgcn_mfma_f32_16x16x32_f16(qf1, kf1, acc, 0, 0, 0);
            s[blk] = acc;
        }
        float alpha[4];
        #pragma unroll
        for (int r = 0; r < 4; ++r) {
            float v0 = fmaxf(fmaxf(s[0][r], s[1][r]), fmaxf(s[2][r], s[3][r]));
            #pragma unroll
            for (int mask = 1; mask < 16; mask <<= 1) v0 = fmaxf(v0, __shfl_xor(v0, mask, 64));
            float mn = fmaxf(mi[r], v0);
            alpha[r] = __expf(mi[r] - mn);
            mi[r] = mn;
        }
        #pragma unroll
        for (int blk = 0; blk < 4; ++blk)
            #pragma unroll
            for (int r = 0; r < 4; ++r) s[blk][r] = __expf(s[blk][r] - mi[r]);
        #pragma unroll
        for (int r = 0; r < 4; ++r) {
            float tt = s[0][r] + s[1][r] + s[2][r] + s[3][r];
            #pragma unroll
            for (int mask = 1; mask < 16; mask <<= 1) tt += __shfl_xor(tt, mask, 64);
            li[r] = li[r] * alpha[r] + tt;
        }
        #pragma unroll
        for (int d = 0; d < 4; ++d)
            #pragma unroll
            for (int r = 0; r < 4; ++r) o[d][r] *= alpha[r];
        #pragma unroll
        for (int blk = 0; blk < 4; ++blk)
            #pragma unroll
            for (int r = 0; r < 4; ++r)
                Pw[wave][quad * 4 + r][blk * 16 + m] = (_Float16)s[blk][r];
        #pragma unroll
        for (int ks = 0; ks < 2; ++ks) {
            half8 af = *(const half8*)&Pw[wave][m][ks * 32 + quad * 8];
            #pragma unroll
            for (int d = 0; d < 4; ++d) {
                half8 bf = *(const half8*)&Vts[d * 16 + m][ks * 32 + quad * 8];
                o[d] = __builtin_amdgcn_mfma_f32_16x16x32_f16(af, bf, o[d], 0, 0, 0);
            }
        }
    }
    #pragma unroll
    for (int d = 0; d < 4; ++d)
        #pragma unroll
        for (int r = 0; r < 4; ++r) {
            const int row = q_base + wave * 16 + quad * 4 + r;
            Out[bh_off + (size_t)row * HD + d * 16 + m] = o[d][r] / li[r];
        }
}

extern "C" void kernel_launch(void* const* d_in, const int* in_sizes, int n_in,
                              void* d_out, int out_size, void* d_ws, size_t ws_size,
                              hipStream_t stream) {
    const float* q = (const float*)d_in[0];
    const float* k = (const float*)d_in[1];
    const float* v = (const float*)d_in[2];
    float* out = (float*)d_out;

    const size_t nelem = (size_t)B * N * H * D;           // 4194304
    const size_t need = 2 * nelem * sizeof(_Float16);     // Kf + Vt

    if (ws_size >= need) {
        _Float16* Kf = (_Float16*)d_ws;
        _Float16* Vtr = Kf + nelem;
        prep_kernel<<<dim3(2048 + 1024), 256, 0, stream>>>(k, v, Kf, Vtr);
        fattn4_kernel<<<dim3((N / QT) * H * B), 256, 0, stream>>>(q, Kf, Vtr, out);
    } else {
        fattn_fb_kernel<<<dim3(N / 64, H, B), 256, 0, stream>>>(q, k, v, out);
    }
}

// Round 5
// 140.915 us; speedup vs baseline: 1.5477x; 1.5477x over previous
//
#include <hip/hip_runtime.h>

// Problem: attention, q,k,v [B=4, N=2048, H=8, D=64] fp32 -> out same.
#define B 4
#define N 2048
#define H 8
#define D 64
#define HD 512              // row stride (elements) for fixed (b,h)
#define QT 128              // q rows per block (4 waves x 32)
#define KT 64               // keys per tile
#define NTILES (N / KT)     // 32
#define PLS 72              // prep-kernel LDS pad stride

typedef _Float16 half8 __attribute__((ext_vector_type(8)));
typedef _Float16 half4 __attribute__((ext_vector_type(4)));
typedef float float4_ __attribute__((ext_vector_type(4)));

// ---------------- fused prepass: K f32->f16 same layout; V -> Vt [b,h,d,n] f16 ----------------
__global__ void prep_kernel(const float* __restrict__ K, const float* __restrict__ V,
                            _Float16* __restrict__ Kf, _Float16* __restrict__ Vtr) {
    __shared__ _Float16 tile[64][PLS];
    const int t = threadIdx.x;
    if (blockIdx.x < 2048) {
        const size_t i = (size_t)blockIdx.x * 256 + t;
        const float4_* p = (const float4_*)(K + i * 8);
        float4_ a = p[0], b = p[1];
        half8 hh;
        #pragma unroll
        for (int j = 0; j < 4; ++j) { hh[j] = (_Float16)a[j]; hh[4 + j] = (_Float16)b[j]; }
        *(half8*)(Kf + i * 8) = hh;
    } else {
        const int bid = blockIdx.x - 2048;
        const int nt = bid & 31, h = (bid >> 5) & 7, b = bid >> 8;
        {
            const int i = t >> 2, c0 = (t & 3) * 16;
            const float* vp = V + (size_t)b * N * HD + (size_t)(nt * 64 + i) * HD + h * D + c0;
            #pragma unroll
            for (int j = 0; j < 4; ++j) {
                float4_ a = *(const float4_*)(vp + j * 4);
                #pragma unroll
                for (int c = 0; c < 4; ++c) tile[i][c0 + j * 4 + c] = (_Float16)a[c];
            }
        }
        __syncthreads();
        {
            const int d = t >> 2, n0 = (t & 3) * 16;
            half8 lo, hi;
            #pragma unroll
            for (int j = 0; j < 8; ++j) { lo[j] = tile[n0 + j][d]; hi[j] = tile[n0 + 8 + j][d]; }
            _Float16* op = Vtr + ((size_t)(b * H + h) * D + d) * N + nt * 64 + n0;
            *(half8*)op = lo;
            *(half8*)(op + 8) = hi;
        }
    }
}

// ---------------- async staging (chunk-swizzled, wave-split) ----------------
__device__ __forceinline__ void stage_k(const _Float16* __restrict__ Kbh, int keybase,
                                        _Float16* kb, int wave, int lane) {
    const int rsub = lane >> 3, slot = lane & 7;
    #pragma unroll
    for (int i = 0; i < 2; ++i) {
        const int row = wave * 16 + i * 8 + rsub;
        const int c = slot ^ (row & 7);
        __builtin_amdgcn_global_load_lds(
            (const __attribute__((address_space(1))) void*)(Kbh + (size_t)(keybase + row) * HD + c * 8),
            (__attribute__((address_space(3))) void*)(kb + (wave * 16 + i * 8) * 64), 16, 0, 0);
    }
}
__device__ __forceinline__ void stage_v(const _Float16* __restrict__ Vbh, int keybase,
                                        _Float16* vb, int wave, int lane) {
    const int rsub = lane >> 3, slot = lane & 7;
    #pragma unroll
    for (int i = 0; i < 2; ++i) {
        const int row = wave * 16 + i * 8 + rsub;      // d row
        const int c = slot ^ (row & 7);
        __builtin_amdgcn_global_load_lds(
            (const __attribute__((address_space(1))) void*)(Vbh + (size_t)row * N + keybase + c * 8),
            (__attribute__((address_space(3))) void*)(vb + (wave * 16 + i * 8) * 64), 16, 0, 0);
    }
}

// ---- S^T = K (Q*sc)^T, P = exp2, column-sum, write P (XOR-swizzled, no pad) ----
__device__ __forceinline__ void do_st(const _Float16* Kt, const half8 qf[2][2],
                                      float lsum[2], _Float16* PwW, int m, int quad) {
    #pragma unroll
    for (int blk = 0; blk < 4; ++blk) {
        const int key = blk * 16 + m;
        half8 kf0 = *(const half8*)(Kt + key * 64 + ((quad ^ (m & 7)) * 8));
        half8 kf1 = *(const half8*)(Kt + key * 64 + (((4 + quad) ^ (m & 7)) * 8));
        #pragma unroll
        for (int u = 0; u < 2; ++u) {
            float4_ acc = {};
            acc = __builtin_amdgcn_mfma_f32_16x16x32_f16(kf0, qf[u][0], acc, 0, 0, 0);
            acc = __builtin_amdgcn_mfma_f32_16x16x32_f16(kf1, qf[u][1], acc, 0, 0, 0);
            half4 pk;
            #pragma unroll
            for (int r = 0; r < 4; ++r) {
                float p = __builtin_amdgcn_exp2f(acc[r]);
                lsum[u] += p;
                pk[r] = (_Float16)p;
            }
            const int kpos = (blk * 16 + quad * 4) ^ ((m & 7) << 3);
            *(half4*)(PwW + (u * 16 + m) * 64 + kpos) = pk;
        }
    }
}

__device__ __forceinline__ void load_af(half8 af[2][2], const _Float16* PwW, int m, int quad) {
    #pragma unroll
    for (int u = 0; u < 2; ++u)
        #pragma unroll
        for (int ks = 0; ks < 2; ++ks)
            af[u][ks] = *(const half8*)(PwW + (u * 16 + m) * 64
                                        + ((ks * 32 + quad * 8) ^ ((m & 7) << 3)));
}

__device__ __forceinline__ void do_pv(const _Float16* Vtile, const half8 af[2][2],
                                      float4_ o[2][4], int m, int quad) {
    #pragma unroll
    for (int ks = 0; ks < 2; ++ks)
        #pragma unroll
        for (int db = 0; db < 4; ++db) {
            half8 bf = *(const half8*)(Vtile + (db * 16 + m) * 64
                                       + ((((ks << 2) + quad) ^ (m & 7)) * 8));
            #pragma unroll
            for (int u = 0; u < 2; ++u)
                o[u][db] = __builtin_amdgcn_mfma_f32_16x16x32_f16(af[u][ks], bf, o[u][db], 0, 0, 0);
        }
}

// ---------------- main: 1-tile software-pipelined flash attention ----------------
__global__ __launch_bounds__(256, 2)
void fattn5_kernel(const float* __restrict__ Q, const _Float16* __restrict__ Kf,
                   const _Float16* __restrict__ Vt, float* __restrict__ Out)
{
    __shared__ __align__(16) _Float16 Kb[2][KT * 64];
    __shared__ __align__(16) _Float16 Vb[2][D * 64];
    __shared__ __align__(16) _Float16 Pw[4][32 * 64];   // per-wave, XOR-swizzled

    const int tid  = threadIdx.x;
    const int wave = tid >> 6;
    const int lane = tid & 63;
    const int m    = lane & 15;
    const int quad = lane >> 4;

    const int h = blockIdx.y;
    const int b = blockIdx.z;
    const int q_base = blockIdx.x * QT + wave * 32;

    const size_t bh_q = (size_t)b * N * HD + (size_t)h * D;
    const _Float16* Kbh = Kf + bh_q;
    const _Float16* Vbh = Vt + (size_t)(b * H + h) * D * N;
    _Float16* PwW = Pw[wave];

    const float SC = 0.125f * 1.4426950408889634f;
    half8 qf[2][2];
    #pragma unroll
    for (int u = 0; u < 2; ++u) {
        const float* qp = Q + bh_q + (size_t)(q_base + u * 16 + m) * HD + quad * 8;
        float4_ a0 = *(const float4_*)qp,        a1 = *(const float4_*)(qp + 4);
        float4_ b0 = *(const float4_*)(qp + 32), b1 = *(const float4_*)(qp + 36);
        #pragma unroll
        for (int jj = 0; jj < 4; ++jj) {
            qf[u][0][jj] = (_Float16)(a0[jj] * SC); qf[u][0][4 + jj] = (_Float16)(a1[jj] * SC);
            qf[u][1][jj] = (_Float16)(b0[jj] * SC); qf[u][1][4 + jj] = (_Float16)(b1[jj] * SC);
        }
    }

    float4_ o[2][4] = {};
    float lsum[2] = {0.f, 0.f};

    // prologue: stage K(0); phase 0 computes S^T(0) only
    stage_k(Kbh, 0, Kb[0], wave, lane);
    __syncthreads();
    stage_k(Kbh, KT, Kb[1], wave, lane);
    stage_v(Vbh, 0, Vb[0], wave, lane);
    do_st(Kb[0], qf, lsum, PwW, m, quad);

    // phases t = 1..31: PV(t-1) || S^T(t)
    for (int t = 1; t < NTILES; ++t) {
        __syncthreads();                       // drains K(t) + V(t-1)
        if (t + 1 < NTILES)
            stage_k(Kbh, (t + 1) * KT, Kb[(t + 1) & 1], wave, lane);
        stage_v(Vbh, t * KT, Vb[t & 1], wave, lane);

        half8 af[2][2];
        load_af(af, PwW, m, quad);             // P(t-1) before it's overwritten
        do_st(Kb[t & 1], qf, lsum, PwW, m, quad);      // S^T(t), writes P(t)
        do_pv(Vb[(t - 1) & 1], af, o, m, quad);        // PV(t-1) — independent stream
    }

    // epilogue: PV(31)
    __syncthreads();                           // drains V(31)
    {
        half8 af[2][2];
        load_af(af, PwW, m, quad);
        do_pv(Vb[(NTILES - 1) & 1], af, o, m, quad);
    }

    // finalize: reduce column sums, broadcast to C-layout rows, store
    float inv[2];
    #pragma unroll
    for (int u = 0; u < 2; ++u) {
        float v = lsum[u];
        v += __shfl_xor(v, 16, 64);
        v += __shfl_xor(v, 32, 64);
        inv[u] = 1.0f / v;
    }
    #pragma unroll
    for (int u = 0; u < 2; ++u) {
        #pragma unroll
        for (int r = 0; r < 4; ++r) {
            const int src = (lane & 48) | (quad * 4 + r);
            const float linv = __shfl(inv[u], src, 64);
            const int row = q_base + u * 16 + quad * 4 + r;
            #pragma unroll
            for (int db = 0; db < 4; ++db)
                Out[bh_q + (size_t)row * HD + db * 16 + m] = o[u][db][r] * linv;
        }
    }
}

// ---------------- fallback (round-1 verified kernel) if ws too small ----------------
__global__ __launch_bounds__(256, 2)
void fattn_fb_kernel(const float* __restrict__ Q, const float* __restrict__ K,
                     const float* __restrict__ V, float* __restrict__ Out)
{
    __shared__ __align__(16) _Float16 Ks[KT][PLS];
    __shared__ __align__(16) _Float16 Vts[D][PLS];
    __shared__ __align__(16) _Float16 Pwf[4][16][PLS];
    const int tid = threadIdx.x, wave = tid >> 6, lane = tid & 63;
    const int m = lane & 15, quad = lane >> 4;
    const int q_base = blockIdx.x * 64;
    const size_t bh_off = ((size_t)blockIdx.z * N * H + (size_t)blockIdx.y) * D;
    const float SCALE = 0.125f;
    const int qrow = q_base + wave * 16 + m;
    const float* qp = Q + bh_off + (size_t)qrow * HD + quad * 8;
    half8 qf0, qf1;
    #pragma unroll
    for (int j = 0; j < 8; ++j) qf0[j] = (_Float16)(qp[j] * SCALE);
    #pragma unroll
    for (int j = 0; j < 8; ++j) qf1[j] = (_Float16)(qp[32 + j] * SCALE);
    float4_ o[4] = {};
    float mi[4], li[4];
    #pragma unroll
    for (int r = 0; r < 4; ++r) { mi[r] = -1e30f; li[r] = 0.0f; }
    for (int kt = 0; kt < N; kt += KT) {
        __syncthreads();
        {
            const int key = tid >> 2, c0 = (tid & 3) * 16;
            const float* kp = K + bh_off + (size_t)(kt + key) * HD + c0;
            half8 lo, hi;
            #pragma unroll
            for (int j = 0; j < 8; ++j) lo[j] = (_Float16)kp[j];
            #pragma unroll
            for (int j = 0; j < 8; ++j) hi[j] = (_Float16)kp[8 + j];
            *(half8*)&Ks[key][c0] = lo;
            *(half8*)&Ks[key][c0 + 8] = hi;
        }
        {
            const int c0 = (tid & 15) * 4, k0 = (tid >> 4) * 4;
            const float* vp = V + bh_off + (size_t)(kt + k0) * HD + c0;
            #pragma unroll
            for (int c = 0; c < 4; ++c)
                #pragma unroll
                for (int i = 0; i < 4; ++i)
                    Vts[c0 + c][k0 + i] = (_Float16)vp[i * HD + c];
        }
        __syncthreads();
        float4_ s[4];
        #pragma unroll
        for (int blk = 0; blk < 4; ++blk) {
            const int key = blk * 16 + m;
            half8 kf0 = *(const half8*)&Ks[key][quad * 8];
            half8 kf1 = *(const half8*)&Ks[key][32 + quad * 8];
            float4_ acc = {};
            acc = __builtin_amdgcn_mfma_f32_16x16x32_f16(qf0, kf0, acc, 0, 0, 0);
            acc = __builtin_amdgcn_mfma_f32_16x16x32_f16(qf1, kf1, acc, 0, 0, 0);
            s[blk] = acc;
        }
        float alpha[4];
        #pragma unroll
        for (int r = 0; r < 4; ++r) {
            float v0 = fmaxf(fmaxf(s[0][r], s[1][r]), fmaxf(s[2][r], s[3][r]));
            #pragma unroll
            for (int mask = 1; mask < 16; mask <<= 1) v0 = fmaxf(v0, __shfl_xor(v0, mask, 64));
            float mn = fmaxf(mi[r], v0);
            alpha[r] = __expf(mi[r] - mn);
            mi[r] = mn;
        }
        #pragma unroll
        for (int blk = 0; blk < 4; ++blk)
            #pragma unroll
            for (int r = 0; r < 4; ++r) s[blk][r] = __expf(s[blk][r] - mi[r]);
        #pragma unroll
        for (int r = 0; r < 4; ++r) {
            float tt = s[0][r] + s[1][r] + s[2][r] + s[3][r];
            #pragma unroll
            for (int mask = 1; mask < 16; mask <<= 1) tt += __shfl_xor(tt, mask, 64);
            li[r] = li[r] * alpha[r] + tt;
        }
        #pragma unroll
        for (int d = 0; d < 4; ++d)
            #pragma unroll
            for (int r = 0; r < 4; ++r) o[d][r] *= alpha[r];
        #pragma unroll
        for (int blk = 0; blk < 4; ++blk)
            #pragma unroll
            for (int r = 0; r < 4; ++r)
                Pwf[wave][quad * 4 + r][blk * 16 + m] = (_Float16)s[blk][r];
        #pragma unroll
        for (int ks = 0; ks < 2; ++ks) {
            half8 af = *(const half8*)&Pwf[wave][m][ks * 32 + quad * 8];
            #pragma unroll
            for (int d = 0; d < 4; ++d) {
                half8 bf = *(const half8*)&Vts[d * 16 + m][ks * 32 + quad * 8];
                o[d] = __builtin_amdgcn_mfma_f32_16x16x32_f16(af, bf, o[d], 0, 0, 0);
            }
        }
    }
    #pragma unroll
    for (int d = 0; d < 4; ++d)
        #pragma unroll
        for (int r = 0; r < 4; ++r) {
            const int row = q_base + wave * 16 + quad * 4 + r;
            Out[bh_off + (size_t)row * HD + d * 16 + m] = o[d][r] / li[r];
        }
}

extern "C" void kernel_launch(void* const* d_in, const int* in_sizes, int n_in,
                              void* d_out, int out_size, void* d_ws, size_t ws_size,
                              hipStream_t stream) {
    const float* q = (const float*)d_in[0];
    const float* k = (const float*)d_in[1];
    const float* v = (const float*)d_in[2];
    float* out = (float*)d_out;

    const size_t nelem = (size_t)B * N * H * D;           // 4194304
    const size_t need = 2 * nelem * sizeof(_Float16);     // Kf + Vt

    if (ws_size >= need) {
        _Float16* Kf = (_Float16*)d_ws;
        _Float16* Vtr = Kf + nelem;
        prep_kernel<<<dim3(2048 + 1024), 256, 0, stream>>>(k, v, Kf, Vtr);
        fattn5_kernel<<<dim3(N / QT, H, B), 256, 0, stream>>>(q, Kf, Vtr, out);
    } else {
        fattn_fb_kernel<<<dim3(N / 64, H, B), 256, 0, stream>>>(q, k, v, out);
    }
}